// Round 11
// baseline (1262.978 us; speedup 1.0000x reference)
//
#include <hip/hip_runtime.h>
#include <hip/hip_bf16.h>
#include <math.h>

#define NN 100000
#define NE 1600000
#define NP 500000
#define HD 128
#define NPB 128                    // nodes per bucket (pow2)
#define NB 782                     // ceil(NN/NPB)
#define CAP 2560                   // bucket capacity (mean 2048, +11 sigma; validated R10)
#define CHUNK 4096                 // edges per binning workgroup
#define NWG 391                    // ceil(NE/CHUNK)
#define AGS 20                     // LDS agg stride (16 feats + 4 pad; 20%32 breaks conflicts)

typedef __attribute__((ext_vector_type(8))) short short8;   // 8 bf16 = 4 VGPRs
typedef __attribute__((ext_vector_type(4))) float f32x4;

// ---- bf16 helpers ----
__device__ __forceinline__ float bf_lo(unsigned int u) { return __uint_as_float(u << 16); }
__device__ __forceinline__ float bf_hi(unsigned int u) { return __uint_as_float(u & 0xffff0000u); }
__device__ __forceinline__ unsigned short bf16_rne(float f) {
  unsigned int u = __float_as_uint(f);
  u = (u + 0x7fffu + ((u >> 16) & 1u)) >> 16;
  return (unsigned short)u;
}

// ---- binA: bin edges by dst-bucket; packed entry = src(17b) | local_dst(7b)<<17 ----
// gcursor zeroed by hipMemsetAsync; holds per-bucket counts after this kernel.
__global__ __launch_bounds__(256) void k_binA(const int* __restrict__ src,
                                              const int* __restrict__ dst,
                                              int* __restrict__ gcursor,
                                              unsigned* __restrict__ binned, int ne) {
  __shared__ int hist[NB];
  __shared__ int base[NB];
  const int t = threadIdx.x;
  const int e0 = blockIdx.x * CHUNK;

  for (int i = t; i < NB; i += 256) hist[i] = 0;
  __syncthreads();

#pragma unroll
  for (int k = 0; k < CHUNK / 256; ++k) {
    int e = e0 + k * 256 + t;
    if (e < ne) atomicAdd(&hist[dst[e] >> 7], 1);
  }
  __syncthreads();

  for (int i = t; i < NB; i += 256) {
    int c = hist[i];
    base[i] = i * CAP + (c ? atomicAdd(&gcursor[i], c) : 0);
    hist[i] = 0;
  }
  __syncthreads();

#pragma unroll
  for (int k = 0; k < CHUNK / 256; ++k) {
    int e = e0 + k * 256 + t;
    if (e < ne) {
      int d = dst[e];
      int b = d >> 7;
      int pos = base[b] + atomicAdd(&hist[b], 1);
      binned[pos] = (unsigned)src[e] | ((unsigned)(d & 127) << 17);
    }
  }
}

// ---- dinv from per-bucket histogram ----
__global__ __launch_bounds__(256) void k_dinvB(const unsigned* __restrict__ binned,
                                               const int* __restrict__ gcursor,
                                               float* __restrict__ dinv) {
  __shared__ int hc[NPB];
  const int b = blockIdx.x;
  const int t = threadIdx.x;
  const int node0 = b * NPB;
  if (t < NPB) hc[t] = 0;
  __syncthreads();
  const int cnt = gcursor[b];
  const int gbase = b * CAP;
  for (int i = t; i < cnt; i += 256) atomicAdd(&hc[binned[gbase + i] >> 17], 1);
  __syncthreads();
  if (t < NPB && node0 + t < NN) dinv[node0 + t] = rsqrtf((float)hc[t] + 1.0f);
}

// ---------------- W transpose+cast: Wt[n][k] = bf16(W[k][n]) ----------------
__global__ void k_wconv(const float* __restrict__ W, unsigned short* __restrict__ Wt) {
  int t = blockIdx.x * 256 + threadIdx.x;  // 16384
  int n = t >> 7, k = t & 127;
  Wt[t] = bf16_rne(W[k * HD + n]);
}

// ---------------- u-vector prep: u1 = W2@Wl[:128], u2 = W2@Wl[128:], c1/c2 = b2.Wl ----------------
// uv layout: [0..127]=u1, [128..255]=u2, [256]=c1, [257]=c2
__global__ __launch_bounds__(256) void k_uvec(const float* __restrict__ W2,
                                              const float* __restrict__ Wl,
                                              const float* __restrict__ b2,
                                              float* __restrict__ uv) {
  __shared__ float sh[256];
  const int t = threadIdx.x;
  const int half = t >> 7;
  const int k = t & 127;
  const float* wl = Wl + half * 128;
  float s = 0.f;
  for (int c = 0; c < 128; ++c) s += W2[k * HD + c] * wl[c];
  uv[half * 128 + k] = s;

  sh[t] = b2[k] * Wl[half * 128 + k];
  __syncthreads();
  for (int o = 64; o > 0; o >>= 1) {
    if ((t & 127) < o) sh[t] += sh[t + o];
    __syncthreads();
  }
  if (t == 0) uv[256] = sh[0];
  if (t == 128) uv[257] = sh[128];
}

// ---------------- MFMA GEMM -> plane layout ----------------
// hsP plane p holds cols [16p,16p+16): ushort addr = ((p*NN + row)*16 + col_in_plane)
__global__ __launch_bounds__(256) void k_gemm_mfma(const float* __restrict__ X,
                                                   const unsigned short* __restrict__ Wt,
                                                   const float* __restrict__ dinv,
                                                   unsigned short* __restrict__ hs,
                                                   int nrows) {
  const int wave = threadIdx.x >> 6;
  const int lane = threadIdx.x & 63;
  const int row0 = blockIdx.x * 64 + wave * 16;
  if (row0 >= nrows) return;
  const int lm = lane & 15;   // A-row / C-col
  const int lq = lane >> 4;   // quad

  int arow = row0 + lm;
  int arowc = arow < nrows ? arow : nrows - 1;  // clamp (stores are guarded)

  short8 afrag[4];
#pragma unroll
  for (int kc = 0; kc < 4; ++kc) {
    int k0 = kc * 32 + lq * 8;
    const float4* p = (const float4*)(X + (size_t)arowc * HD + k0);
    float4 f0 = p[0], f1 = p[1];
    short8 a;
    a[0] = (short)bf16_rne(f0.x); a[1] = (short)bf16_rne(f0.y);
    a[2] = (short)bf16_rne(f0.z); a[3] = (short)bf16_rne(f0.w);
    a[4] = (short)bf16_rne(f1.x); a[5] = (short)bf16_rne(f1.y);
    a[6] = (short)bf16_rne(f1.z); a[7] = (short)bf16_rne(f1.w);
    afrag[kc] = a;
  }

  float dv[4];
#pragma unroll
  for (int r = 0; r < 4; ++r) {
    int row = row0 + lq * 4 + r;
    dv[r] = dinv[row < nrows ? row : 0];
  }

#pragma unroll
  for (int nt = 0; nt < 8; ++nt) {
    f32x4 acc = {0.f, 0.f, 0.f, 0.f};
    const unsigned short* Wb = Wt + (size_t)(nt * 16 + lm) * HD + lq * 8;
#pragma unroll
    for (int kc = 0; kc < 4; ++kc) {
      short8 bfrag = *(const short8*)(Wb + kc * 32);
      acc = __builtin_amdgcn_mfma_f32_16x16x32_bf16(afrag[kc], bfrag, acc, 0, 0, 0);
    }
#pragma unroll
    for (int r = 0; r < 4; ++r) {
      int row = row0 + lq * 4 + r;
      if (row < nrows)
        hs[((size_t)nt * NN + row) * 16 + lm] = bf16_rne(acc[r] * dv[r]);
    }
  }
}

// ---------------- aggQ: bucket x plane aggregation + fused score-projection ----------------
// block = (bucket g, plane x = blockIdx&7). Under round-robin blockIdx->XCD, each XCD
// reads only its 3.2MB plane -> L2-resident random gather. LDS agg 128x16 fp32.
// qpart[x][node] = partial (h.u1, h.u2) over features [16x,16x+16), h = relu(di*agg+b1).
__global__ __launch_bounds__(256) void k_aggQ(const uint4* __restrict__ hsP,
                                              const float* __restrict__ dinv,
                                              const unsigned* __restrict__ binned,
                                              const int* __restrict__ gcursor,
                                              const float* __restrict__ b1,
                                              const float* __restrict__ uv,
                                              float2* __restrict__ qpart) {
  __shared__ unsigned eb[CAP];
  __shared__ float agg[NPB * AGS];
  const int x = blockIdx.x & 7;
  const int g = blockIdx.x >> 3;
  const int t = threadIdx.x;
  const int node0 = g * NPB;
  const int cnt = gcursor[g];
  const int gbase = g * CAP;

  // stage this bucket's edges
  for (int i = t; i < cnt; i += 256) eb[i] = binned[gbase + i];

  // init agg with self rows of plane x (streaming)
  for (int idx = t; idx < NPB * 2; idx += 256) {
    int row = idx >> 1, part = idx & 1;
    int node = node0 + row;
    float v0 = 0.f, v1 = 0.f, v2 = 0.f, v3 = 0.f, v4 = 0.f, v5 = 0.f, v6 = 0.f, v7 = 0.f;
    if (node < NN) {
      uint4 u = hsP[((size_t)x * NN + node) * 2 + part];
      v0 = bf_lo(u.x); v1 = bf_hi(u.x); v2 = bf_lo(u.y); v3 = bf_hi(u.y);
      v4 = bf_lo(u.z); v5 = bf_hi(u.z); v6 = bf_lo(u.w); v7 = bf_hi(u.w);
    }
    float* ap = &agg[row * AGS + part * 8];
    ap[0] = v0; ap[1] = v1; ap[2] = v2; ap[3] = v3;
    ap[4] = v4; ap[5] = v5; ap[6] = v6; ap[7] = v7;
  }
  __syncthreads();

  // main: 32 edges per wave-instruction (lane = eslot*2 + fq; 16B = 8 feats per lane)
  const int w = t >> 6, l = t & 63;
  const int eslot = l >> 1, fq = l & 1;
  for (int i0 = w * 32; i0 < cnt; i0 += 128) {
    int it = i0 + eslot;
    if (it < cnt) {
      unsigned en = eb[it];
      int s = en & 0x1FFFF;
      int ld = en >> 17;
      uint4 u = hsP[((size_t)x * NN + s) * 2 + fq];
      float* ap = &agg[ld * AGS + fq * 8];
      atomicAdd(ap + 0, bf_lo(u.x)); atomicAdd(ap + 1, bf_hi(u.x));
      atomicAdd(ap + 2, bf_lo(u.y)); atomicAdd(ap + 3, bf_hi(u.y));
      atomicAdd(ap + 4, bf_lo(u.z)); atomicAdd(ap + 5, bf_hi(u.z));
      atomicAdd(ap + 6, bf_lo(u.w)); atomicAdd(ap + 7, bf_hi(u.w));
    }
  }
  __syncthreads();

  // epilogue: 2 threads per node, 8 features each
  const int i = t >> 1, half = t & 1;
  const int node = node0 + i;
  float s1 = 0.f, s2 = 0.f;
  if (node < NN) {
    float di = dinv[node];
#pragma unroll
    for (int j = 0; j < 8; ++j) {
      int f = x * 16 + half * 8 + j;
      float h = fmaxf(di * agg[i * AGS + half * 8 + j] + b1[f], 0.f);
      s1 += h * uv[f];
      s2 += h * uv[128 + f];
    }
  }
  s1 += __shfl_xor(s1, 1);
  s2 += __shfl_xor(s2, 1);
  if (half == 0 && node < NN) qpart[(size_t)x * NN + node] = make_float2(s1, s2);
}

// ---------------- qred: q[n] = dinv[n] * sum_x qpart[x][n] ----------------
__global__ void k_qred(const float2* __restrict__ qpart, const float* __restrict__ dinv,
                       float2* __restrict__ q, int n) {
  int i = blockIdx.x * 256 + threadIdx.x;
  if (i < n) {
    float a = 0.f, b = 0.f;
#pragma unroll
    for (int x = 0; x < 8; ++x) {
      float2 p = qpart[(size_t)x * NN + i];
      a += p.x; b += p.y;
    }
    float di = dinv[i];
    q[i] = make_float2(di * a, di * b);
  }
}

// ---------------- qagg2: conv2+score collapsed, bucket-wise (q table L2-resident) ----------------
__global__ __launch_bounds__(256) void k_qagg2(const float2* __restrict__ q,
                                               const float* __restrict__ dinv,
                                               const unsigned* __restrict__ binned,
                                               const int* __restrict__ gcursor,
                                               const float* __restrict__ uv,
                                               float2* __restrict__ sv) {
  __shared__ float accx[NPB];
  __shared__ float accy[NPB];
  const int b = blockIdx.x;
  const int t = threadIdx.x;
  const int node0 = b * NPB;
  if (t < NPB) { accx[t] = 0.f; accy[t] = 0.f; }
  __syncthreads();
  const int cnt = gcursor[b];
  const int gbase = b * CAP;
  for (int i = t; i < cnt; i += 256) {
    unsigned en = binned[gbase + i];
    float2 qq = q[en & 0x1FFFF];
    int ld = en >> 17;
    atomicAdd(&accx[ld], qq.x);
    atomicAdd(&accy[ld], qq.y);
  }
  __syncthreads();
  if (t < NPB && node0 + t < NN) {
    int node = node0 + t;
    float di = dinv[node];
    float2 qs = q[node];
    sv[node] = make_float2(di * (accx[t] + qs.x) + uv[256],
                           di * (accy[t] + qs.y) + uv[257]);
  }
}

// ---------------- pair outputs ----------------
__global__ void k_pairs(const float2* __restrict__ s, const int* __restrict__ I,
                        const int* __restrict__ J, const float* __restrict__ blin,
                        float* __restrict__ out, int np) {
  int p = blockIdx.x * 256 + threadIdx.x;
  if (p < np) {
    float v = s[I[p]].x + s[J[p]].y + blin[0];
    out[p] = 1.f / (1.f + __expf(-v));
  }
}

extern "C" void kernel_launch(void* const* d_in, const int* in_sizes, int n_in,
                              void* d_out, int out_size, void* d_ws, size_t ws_size,
                              hipStream_t stream) {
  const float* x     = (const float*)d_in[0];
  const int*   eidx  = (const int*)d_in[1];
  const int*   Iidx  = (const int*)d_in[2];
  const int*   Jidx  = (const int*)d_in[3];
  const float* W1    = (const float*)d_in[4];
  const float* b1    = (const float*)d_in[5];
  const float* W2    = (const float*)d_in[6];
  const float* b2    = (const float*)d_in[7];
  const float* Wlin  = (const float*)d_in[8];
  const float* blin  = (const float*)d_in[9];
  const int* src = eidx;
  const int* dst = eidx + NE;

  // workspace layout (float offsets; all 16B-aligned where needed)
  float* ws    = (float*)d_ws;
  float* dinv  = ws;                                  // 100000
  float* qbuf  = dinv + 100000;                       // 200000 (float2/node)
  float* sv    = qbuf + 200000;                       // 200000 (float2/node)
  float* uv    = sv + 200000;                         // 264
  float* qpart = uv + 264;                            // 8*NN float2 = 1600000
  unsigned short* hs = (unsigned short*)(qpart + 1600000);  // 8 planes * NN * 16 bf16
  unsigned short* wt1 = hs + (size_t)NN * HD;         // 16384 bf16
  int* gcursor = (int*)(wt1 + 16384);                 // NB (pad 784)
  unsigned* binned = (unsigned*)(gcursor + 784);      // NB*CAP = 2001920 x 4B

  float* out = (float*)d_out;

  // ---- build binned buckets ----
  hipMemsetAsync(gcursor, 0, NB * sizeof(int), stream);
  k_binA<<<NWG, 256, 0, stream>>>(src, dst, gcursor, binned, NE);
  k_dinvB<<<NB, 256, 0, stream>>>(binned, gcursor, dinv);

  // ---- weight prep ----
  k_wconv<<<64, 256, 0, stream>>>(W1, wt1);
  k_uvec<<<1, 256, 0, stream>>>(W2, Wlin, b2, uv);

  // conv1 GEMM -> plane-layout hs
  k_gemm_mfma<<<(NN + 63) / 64, 256, 0, stream>>>(x, wt1, dinv, hs, NN);

  // conv1 aggregation + relu + score projection (plane-sharded)
  k_aggQ<<<NB * 8, 256, 0, stream>>>((const uint4*)hs, dinv, binned, gcursor, b1, uv,
                                     (float2*)qpart);
  k_qred<<<(NN + 255) / 256, 256, 0, stream>>>((const float2*)qpart, dinv, (float2*)qbuf, NN);

  // conv2 + score head collapsed
  k_qagg2<<<NB, 256, 0, stream>>>((const float2*)qbuf, dinv, binned, gcursor, uv, (float2*)sv);

  // pair outputs
  k_pairs<<<(NP + 255) / 256, 256, 0, stream>>>((const float2*)sv, Iidx, Jidx, blin, out, NP);
}

// Round 12
// 557.168 us; speedup vs baseline: 2.2668x; 2.2668x over previous
//
#include <hip/hip_runtime.h>
#include <hip/hip_bf16.h>
#include <math.h>

#define NN 100000
#define NE 1600000
#define NP 500000
#define HD 128
#define NPB 128                    // nodes per bucket (pow2)
#define NB 782                     // ceil(NN/NPB)
#define CAP 2560                   // bucket capacity (mean 2048, +11 sigma; validated R10)
#define CHUNK 4096                 // edges per binning workgroup
#define NWG 391                    // ceil(NE/CHUNK)

typedef __attribute__((ext_vector_type(8))) short short8;   // 8 bf16 = 4 VGPRs
typedef __attribute__((ext_vector_type(4))) float f32x4;

// ---- bf16 helpers ----
__device__ __forceinline__ float bf_lo(unsigned int u) { return __uint_as_float(u << 16); }
__device__ __forceinline__ float bf_hi(unsigned int u) { return __uint_as_float(u & 0xffff0000u); }
__device__ __forceinline__ unsigned short bf16_rne(float f) {
  unsigned int u = __float_as_uint(f);
  u = (u + 0x7fffu + ((u >> 16) & 1u)) >> 16;
  return (unsigned short)u;
}
// accumulate 8 bf16 (one uint4) into ax[8]
__device__ __forceinline__ void acc_row8(float* ax, uint4 u) {
  ax[0] += bf_lo(u.x); ax[1] += bf_hi(u.x);
  ax[2] += bf_lo(u.y); ax[3] += bf_hi(u.y);
  ax[4] += bf_lo(u.z); ax[5] += bf_hi(u.z);
  ax[6] += bf_lo(u.w); ax[7] += bf_hi(u.w);
}

// ---------------- cursor init: gcursor[b] = b*CAP ----------------
__global__ void k_initgcur(int* __restrict__ gcursor) {
  int b = blockIdx.x * 256 + threadIdx.x;
  if (b < NB) gcursor[b] = b * CAP;
}

// ---- binA: bin edges into fixed-capacity bucket regions (8B entries) ----
__global__ __launch_bounds__(256) void k_binA(const int* __restrict__ src,
                                              const int* __restrict__ dst,
                                              int* __restrict__ gcursor,
                                              uint2* __restrict__ binned, int ne) {
  __shared__ int hist[NB];
  __shared__ int base[NB];
  const int t = threadIdx.x;
  const int e0 = blockIdx.x * CHUNK;

  for (int i = t; i < NB; i += 256) hist[i] = 0;
  __syncthreads();

#pragma unroll
  for (int k = 0; k < CHUNK / 256; ++k) {
    int e = e0 + k * 256 + t;
    if (e < ne) atomicAdd(&hist[dst[e] >> 7], 1);
  }
  __syncthreads();

  for (int i = t; i < NB; i += 256) {
    int c = hist[i];
    base[i] = c ? atomicAdd(&gcursor[i], c) : 0;
    hist[i] = 0;
  }
  __syncthreads();

#pragma unroll
  for (int k = 0; k < CHUNK / 256; ++k) {
    int e = e0 + k * 256 + t;
    if (e < ne) {
      int d = dst[e];
      int b = d >> 7;
      int pos = base[b] + atomicAdd(&hist[b], 1);
      binned[pos] = make_uint2((unsigned int)src[e], (unsigned int)d);
    }
  }
}

// ---- binB: per-node count (LDS) -> rows(start,end) + dinv, then CSR placement ----
__global__ __launch_bounds__(256) void k_binB(const uint2* __restrict__ binned,
                                              const int* __restrict__ gcursor,
                                              int2* __restrict__ rows,
                                              int* __restrict__ col,
                                              float* __restrict__ dinv) {
  __shared__ int hcnt[NPB];
  __shared__ int sc[NPB];
  __shared__ int lcur[NPB];
  const int b = blockIdx.x;
  const int t = threadIdx.x;
  const int node0 = b * NPB;
  const int node1 = (node0 + NPB > NN) ? NN : node0 + NPB;
  const int nnode = node1 - node0;
  if (t < NPB) hcnt[t] = 0;
  __syncthreads();

  const int gbase = b * CAP;
  const int gend = gcursor[b];   // after binA: b*CAP + bucket count
  for (int i = gbase + t; i < gend; i += 256)
    atomicAdd(&hcnt[binned[i].y - node0], 1);
  __syncthreads();

  int v = (t < NPB) ? hcnt[t] : 0;
  if (t < NPB) sc[t] = v;
  __syncthreads();
#pragma unroll
  for (int o = 1; o < NPB; o <<= 1) {
    int add = (t < NPB && t >= o) ? sc[t - o] : 0;
    __syncthreads();
    if (t < NPB) sc[t] += add;
    __syncthreads();
  }
  if (t < nnode) {
    int rp = gbase + sc[t] - v;   // exclusive prefix within bucket
    rows[node0 + t] = make_int2(rp, rp + v);
    lcur[t] = rp;
    dinv[node0 + t] = rsqrtf((float)v + 1.0f);
  }
  __syncthreads();

  for (int i = gbase + t; i < gend; i += 256) {
    uint2 p = binned[i];
    int pos = atomicAdd(&lcur[p.y - node0], 1);
    col[pos] = (int)p.x;
  }
}

// ---------------- W transpose+cast: Wt[n][k] = bf16(W[k][n]) ----------------
__global__ void k_wconv(const float* __restrict__ W, unsigned short* __restrict__ Wt) {
  int t = blockIdx.x * 256 + threadIdx.x;  // 16384
  int n = t >> 7, k = t & 127;
  Wt[t] = bf16_rne(W[k * HD + n]);
}

// ---------------- u-vector prep: u1 = W2@Wl[:128], u2 = W2@Wl[128:], c1/c2 = b2.Wl ----------------
// uv layout: [0..127]=u1, [128..255]=u2, [256]=c1, [257]=c2
__global__ __launch_bounds__(256) void k_uvec(const float* __restrict__ W2,
                                              const float* __restrict__ Wl,
                                              const float* __restrict__ b2,
                                              float* __restrict__ uv) {
  __shared__ float sh[256];
  const int t = threadIdx.x;
  const int half = t >> 7;
  const int k = t & 127;
  const float* wl = Wl + half * 128;
  float s = 0.f;
  for (int c = 0; c < 128; ++c) s += W2[k * HD + c] * wl[c];
  uv[half * 128 + k] = s;

  sh[t] = b2[k] * Wl[half * 128 + k];
  __syncthreads();
  for (int o = 64; o > 0; o >>= 1) {
    if ((t & 127) < o) sh[t] += sh[t + o];
    __syncthreads();
  }
  if (t == 0) uv[256] = sh[0];
  if (t == 128) uv[257] = sh[128];
}

// ---------------- MFMA GEMM -> plane layout ----------------
// plane p holds cols [16p,16p+16): ushort addr = ((p*NN + row)*16 + col_in_plane)
__global__ __launch_bounds__(256) void k_gemm_mfma(const float* __restrict__ X,
                                                   const unsigned short* __restrict__ Wt,
                                                   const float* __restrict__ dinv,
                                                   unsigned short* __restrict__ hs,
                                                   int nrows) {
  const int wave = threadIdx.x >> 6;
  const int lane = threadIdx.x & 63;
  const int row0 = blockIdx.x * 64 + wave * 16;
  if (row0 >= nrows) return;
  const int lm = lane & 15;   // A-row / C-col
  const int lq = lane >> 4;   // quad

  int arow = row0 + lm;
  int arowc = arow < nrows ? arow : nrows - 1;  // clamp (stores are guarded)

  short8 afrag[4];
#pragma unroll
  for (int kc = 0; kc < 4; ++kc) {
    int k0 = kc * 32 + lq * 8;
    const float4* p = (const float4*)(X + (size_t)arowc * HD + k0);
    float4 f0 = p[0], f1 = p[1];
    short8 a;
    a[0] = (short)bf16_rne(f0.x); a[1] = (short)bf16_rne(f0.y);
    a[2] = (short)bf16_rne(f0.z); a[3] = (short)bf16_rne(f0.w);
    a[4] = (short)bf16_rne(f1.x); a[5] = (short)bf16_rne(f1.y);
    a[6] = (short)bf16_rne(f1.z); a[7] = (short)bf16_rne(f1.w);
    afrag[kc] = a;
  }

  float dv[4];
#pragma unroll
  for (int r = 0; r < 4; ++r) {
    int row = row0 + lq * 4 + r;
    dv[r] = dinv[row < nrows ? row : 0];
  }

#pragma unroll
  for (int nt = 0; nt < 8; ++nt) {
    f32x4 acc = {0.f, 0.f, 0.f, 0.f};
    const unsigned short* Wb = Wt + (size_t)(nt * 16 + lm) * HD + lq * 8;
#pragma unroll
    for (int kc = 0; kc < 4; ++kc) {
      short8 bfrag = *(const short8*)(Wb + kc * 32);
      acc = __builtin_amdgcn_mfma_f32_16x16x32_bf16(afrag[kc], bfrag, acc, 0, 0, 0);
    }
#pragma unroll
    for (int r = 0; r < 4; ++r) {
      int row = row0 + lq * 4 + r;
      if (row < nrows)
        hs[((size_t)nt * NN + row) * 16 + lm] = bf16_rne(acc[r] * dv[r]);
    }
  }
}

// ---------------- plane-sharded gather + relu + fused score-projection ----------------
// Block = 4 waves; wave = one node, one plane x = blockIdx&7 (round-robin -> XCD x
// reads only its 3.2MB plane: L2-resident random gather — confirmed by R11 FETCH).
// lane = eslot*2 + fq: 32 edges in flight, 16B/lane. REGISTER accumulation
// (R11's LDS atomics died on bank conflicts: 600k SQ_LDS_BANK_CONFLICT, 1069us).
// qpart[x][node] = partial (h.u1, h.u2) over feats [16x,16x+16), h = relu(di*agg+b1).
__global__ __launch_bounds__(256) void k_gather1qp(const uint4* __restrict__ hsP,
                                                   const float* __restrict__ dinv,
                                                   const int2* __restrict__ rows,
                                                   const int* __restrict__ col,
                                                   const float* __restrict__ b1,
                                                   const float* __restrict__ uv,
                                                   float2* __restrict__ qpart) {
  const int x = blockIdx.x & 7;
  const int node = (blockIdx.x >> 3) * 4 + (threadIdx.x >> 6);
  if (node >= NN) return;
  const int lane = threadIdx.x & 63;
  const int eslot = lane >> 1;
  const int fq = lane & 1;

  int2 be = rows[node];
  const uint4* plane = hsP + (size_t)x * NN * 2 + fq;

  float ax[8] = {0.f, 0.f, 0.f, 0.f, 0.f, 0.f, 0.f, 0.f};
  if (eslot == 0) acc_row8(ax, plane[(size_t)node * 2]);  // self term (lanes 0,1)

  for (int e = be.x + eslot; e < be.y; e += 32) {
    int s = col[e];
    acc_row8(ax, plane[(size_t)s * 2]);
  }

  // reduce across the 32 edge slots (lane bits 1..5)
#pragma unroll
  for (int o = 2; o <= 32; o <<= 1) {
#pragma unroll
    for (int i = 0; i < 8; ++i) ax[i] += __shfl_xor(ax[i], o);
  }

  // epilogue: every lane computes its fq-half partial projection
  float di = dinv[node];
  float s1 = 0.f, s2 = 0.f;
#pragma unroll
  for (int j = 0; j < 8; ++j) {
    int f = x * 16 + fq * 8 + j;
    float h = fmaxf(di * ax[j] + b1[f], 0.f);
    s1 += h * uv[f];
    s2 += h * uv[128 + f];
  }
  s1 += __shfl_xor(s1, 1);
  s2 += __shfl_xor(s2, 1);
  if (lane == 0) qpart[(size_t)x * NN + node] = make_float2(s1, s2);
}

// ---------------- qred: q[n] = dinv[n] * sum_x qpart[x][n] ----------------
__global__ void k_qred(const float2* __restrict__ qpart, const float* __restrict__ dinv,
                       float2* __restrict__ q, int n) {
  int i = blockIdx.x * 256 + threadIdx.x;
  if (i < n) {
    float a = 0.f, b = 0.f;
#pragma unroll
    for (int xx = 0; xx < 8; ++xx) {
      float2 p = qpart[(size_t)xx * NN + i];
      a += p.x; b += p.y;
    }
    float di = dinv[i];
    q[i] = make_float2(di * a, di * b);
  }
}

// ---------------- qagg: conv2+score collapsed (q table 800KB, L2-resident) ----------------
__global__ __launch_bounds__(256) void k_qagg(const float2* __restrict__ q,
                                              const float* __restrict__ dinv,
                                              const int2* __restrict__ rows,
                                              const int* __restrict__ col,
                                              const float* __restrict__ uv,
                                              float2* __restrict__ sv, int n) {
  int i = blockIdx.x * 256 + threadIdx.x;
  if (i >= n) return;
  int2 be = rows[i];
  int beg = be.x, end = be.y;
  float2 a = q[i];
  float a1 = a.x, a2 = a.y;
  int e = beg;
  for (; e + 3 < end; e += 4) {
    float2 q0 = q[col[e]];
    float2 q1 = q[col[e + 1]];
    float2 q2 = q[col[e + 2]];
    float2 q3 = q[col[e + 3]];
    a1 += (q0.x + q1.x) + (q2.x + q3.x);
    a2 += (q0.y + q1.y) + (q2.y + q3.y);
  }
  for (; e < end; ++e) {
    float2 qq = q[col[e]];
    a1 += qq.x; a2 += qq.y;
  }
  float di = dinv[i];
  sv[i] = make_float2(a1 * di + uv[256], a2 * di + uv[257]);
}

// ---------------- pair outputs ----------------
__global__ void k_pairs(const float2* __restrict__ s, const int* __restrict__ I,
                        const int* __restrict__ J, const float* __restrict__ blin,
                        float* __restrict__ out, int np) {
  int p = blockIdx.x * 256 + threadIdx.x;
  if (p < np) {
    float v = s[I[p]].x + s[J[p]].y + blin[0];
    out[p] = 1.f / (1.f + __expf(-v));
  }
}

extern "C" void kernel_launch(void* const* d_in, const int* in_sizes, int n_in,
                              void* d_out, int out_size, void* d_ws, size_t ws_size,
                              hipStream_t stream) {
  const float* x     = (const float*)d_in[0];
  const int*   eidx  = (const int*)d_in[1];
  const int*   Iidx  = (const int*)d_in[2];
  const int*   Jidx  = (const int*)d_in[3];
  const float* W1    = (const float*)d_in[4];
  const float* b1    = (const float*)d_in[5];
  const float* W2    = (const float*)d_in[6];
  const float* b2    = (const float*)d_in[7];
  const float* Wlin  = (const float*)d_in[8];
  const float* blin  = (const float*)d_in[9];
  const int* src = eidx;
  const int* dst = eidx + NE;

  // workspace layout
  float* ws    = (float*)d_ws;
  float* dinv  = ws;                                  // 100000
  float* sv    = dinv + 100000;                       // 200000 (float2/node)
  float* qbuf  = sv + 200000;                         // 200000 (float2/node)
  float* uv    = qbuf + 200000;                       // 264
  float* qpart = uv + 264;                            // 8*NN float2 = 1600000
  unsigned short* hs = (unsigned short*)(qpart + 1600000);  // 8 planes * NN * 16 bf16
  unsigned short* wt1 = hs + (size_t)NN * HD;         // 16384 bf16
  int2* rows   = (int2*)(wt1 + 16384);                // NN int2 (8B-aligned)
  int* col     = (int*)(rows + NN);                   // NB*CAP = 2001920
  int* gcursor = col + NB * CAP;                      // NB (pad 784)
  uint2* binned = (uint2*)(gcursor + 784);            // NB*CAP x 8B

  float* out = (float*)d_out;

  // ---- CSR build (fixed-capacity buckets) ----
  k_initgcur<<<(NB + 255) / 256, 256, 0, stream>>>(gcursor);
  k_binA<<<NWG, 256, 0, stream>>>(src, dst, gcursor, binned, NE);
  k_binB<<<NB, 256, 0, stream>>>(binned, gcursor, rows, col, dinv);

  // ---- weight prep ----
  k_wconv<<<64, 256, 0, stream>>>(W1, wt1);
  k_uvec<<<1, 256, 0, stream>>>(W2, Wlin, b2, uv);

  // conv1 GEMM -> plane-layout hs
  k_gemm_mfma<<<(NN + 63) / 64, 256, 0, stream>>>(x, wt1, dinv, hs, NN);

  // conv1 aggregation + relu + score projection (plane-sharded, register acc)
  k_gather1qp<<<((NN + 3) / 4) * 8, 256, 0, stream>>>((const uint4*)hs, dinv, rows, col,
                                                      b1, uv, (float2*)qpart);
  k_qred<<<(NN + 255) / 256, 256, 0, stream>>>((const float2*)qpart, dinv, (float2*)qbuf, NN);

  // conv2 + score head collapsed
  k_qagg<<<(NN + 255) / 256, 256, 0, stream>>>((const float2*)qbuf, dinv, rows, col, uv,
                                               (float2*)sv, NN);

  // pair outputs
  k_pairs<<<(NP + 255) / 256, 256, 0, stream>>>((const float2*)sv, Iidx, Jidx, blin, out, NP);
}

// Round 13
// 282.611 us; speedup vs baseline: 4.4690x; 1.9715x over previous
//
#include <hip/hip_runtime.h>
#include <hip/hip_bf16.h>
#include <math.h>

#define NN 100000
#define NE 1600000
#define NP 500000
#define HD 128
#define NPB 128                    // nodes per bucket (pow2)
#define NB 782                     // ceil(NN/NPB)
#define CAP 2560                   // bucket capacity (mean 2048, +11 sigma; validated R10-12)
#define CHUNK 4096                 // edges per binning workgroup
#define NWG 391                    // ceil(NE/CHUNK)

typedef __attribute__((ext_vector_type(8))) short short8;   // 8 bf16 = 4 VGPRs
typedef __attribute__((ext_vector_type(4))) float f32x4;

// ---- bf16 helpers ----
__device__ __forceinline__ float bf_lo(unsigned int u) { return __uint_as_float(u << 16); }
__device__ __forceinline__ float bf_hi(unsigned int u) { return __uint_as_float(u & 0xffff0000u); }
__device__ __forceinline__ unsigned short bf16_rne(float f) {
  unsigned int u = __float_as_uint(f);
  u = (u + 0x7fffu + ((u >> 16) & 1u)) >> 16;
  return (unsigned short)u;
}
// accumulate 8 bf16 (one uint4) into ax[8]
__device__ __forceinline__ void acc_row8(float* ax, uint4 u) {
  ax[0] += bf_lo(u.x); ax[1] += bf_hi(u.x);
  ax[2] += bf_lo(u.y); ax[3] += bf_hi(u.y);
  ax[4] += bf_lo(u.z); ax[5] += bf_hi(u.z);
  ax[6] += bf_lo(u.w); ax[7] += bf_hi(u.w);
}

// ---------------- cursor init: gcursor[b] = b*CAP ----------------
__global__ void k_initgcur(int* __restrict__ gcursor) {
  int b = blockIdx.x * 256 + threadIdx.x;
  if (b < NB) gcursor[b] = b * CAP;
}

// ---- binA: bin edges into fixed-capacity bucket regions (8B entries) ----
__global__ __launch_bounds__(256) void k_binA(const int* __restrict__ src,
                                              const int* __restrict__ dst,
                                              int* __restrict__ gcursor,
                                              uint2* __restrict__ binned, int ne) {
  __shared__ int hist[NB];
  __shared__ int base[NB];
  const int t = threadIdx.x;
  const int e0 = blockIdx.x * CHUNK;

  for (int i = t; i < NB; i += 256) hist[i] = 0;
  __syncthreads();

#pragma unroll
  for (int k = 0; k < CHUNK / 256; ++k) {
    int e = e0 + k * 256 + t;
    if (e < ne) atomicAdd(&hist[dst[e] >> 7], 1);
  }
  __syncthreads();

  for (int i = t; i < NB; i += 256) {
    int c = hist[i];
    base[i] = c ? atomicAdd(&gcursor[i], c) : 0;
    hist[i] = 0;
  }
  __syncthreads();

#pragma unroll
  for (int k = 0; k < CHUNK / 256; ++k) {
    int e = e0 + k * 256 + t;
    if (e < ne) {
      int d = dst[e];
      int b = d >> 7;
      int pos = base[b] + atomicAdd(&hist[b], 1);
      binned[pos] = make_uint2((unsigned int)src[e], (unsigned int)d);
    }
  }
}

// ---- binB: per-node count (LDS) -> rows(start,end) + dinv, then CSR placement ----
__global__ __launch_bounds__(256) void k_binB(const uint2* __restrict__ binned,
                                              const int* __restrict__ gcursor,
                                              int2* __restrict__ rows,
                                              int* __restrict__ col,
                                              float* __restrict__ dinv) {
  __shared__ int hcnt[NPB];
  __shared__ int sc[NPB];
  __shared__ int lcur[NPB];
  const int b = blockIdx.x;
  const int t = threadIdx.x;
  const int node0 = b * NPB;
  const int node1 = (node0 + NPB > NN) ? NN : node0 + NPB;
  const int nnode = node1 - node0;
  if (t < NPB) hcnt[t] = 0;
  __syncthreads();

  const int gbase = b * CAP;
  const int gend = gcursor[b];   // after binA: b*CAP + bucket count
  for (int i = gbase + t; i < gend; i += 256)
    atomicAdd(&hcnt[binned[i].y - node0], 1);
  __syncthreads();

  int v = (t < NPB) ? hcnt[t] : 0;
  if (t < NPB) sc[t] = v;
  __syncthreads();
#pragma unroll
  for (int o = 1; o < NPB; o <<= 1) {
    int add = (t < NPB && t >= o) ? sc[t - o] : 0;
    __syncthreads();
    if (t < NPB) sc[t] += add;
    __syncthreads();
  }
  if (t < nnode) {
    int rp = gbase + sc[t] - v;   // exclusive prefix within bucket
    rows[node0 + t] = make_int2(rp, rp + v);
    lcur[t] = rp;
    dinv[node0 + t] = rsqrtf((float)v + 1.0f);
  }
  __syncthreads();

  for (int i = gbase + t; i < gend; i += 256) {
    uint2 p = binned[i];
    int pos = atomicAdd(&lcur[p.y - node0], 1);
    col[pos] = (int)p.x;
  }
}

// ---------------- W transpose+cast: Wt[n][k] = bf16(W[k][n]) ----------------
__global__ void k_wconv(const float* __restrict__ W, unsigned short* __restrict__ Wt) {
  int t = blockIdx.x * 256 + threadIdx.x;  // 16384
  int n = t >> 7, k = t & 127;
  Wt[t] = bf16_rne(W[k * HD + n]);
}

// ---------------- u-vector prep: u1 = W2@Wl[:128], u2 = W2@Wl[128:], c1/c2 = b2.Wl ----------------
// uv layout: [0..127]=u1, [128..255]=u2, [256]=c1, [257]=c2
__global__ __launch_bounds__(256) void k_uvec(const float* __restrict__ W2,
                                              const float* __restrict__ Wl,
                                              const float* __restrict__ b2,
                                              float* __restrict__ uv) {
  __shared__ float sh[256];
  const int t = threadIdx.x;
  const int half = t >> 7;
  const int k = t & 127;
  const float* wl = Wl + half * 128;
  float s = 0.f;
  for (int c = 0; c < 128; ++c) s += W2[k * HD + c] * wl[c];
  uv[half * 128 + k] = s;

  sh[t] = b2[k] * Wl[half * 128 + k];
  __syncthreads();
  for (int o = 64; o > 0; o >>= 1) {
    if ((t & 127) < o) sh[t] += sh[t + o];
    __syncthreads();
  }
  if (t == 0) uv[256] = sh[0];
  if (t == 128) uv[257] = sh[128];
}

// ---------------- MFMA GEMM -> plane layout ----------------
// plane p holds cols [16p,16p+16): ushort addr = ((p*NN + row)*16 + col_in_plane)
__global__ __launch_bounds__(256) void k_gemm_mfma(const float* __restrict__ X,
                                                   const unsigned short* __restrict__ Wt,
                                                   const float* __restrict__ dinv,
                                                   unsigned short* __restrict__ hs,
                                                   int nrows) {
  const int wave = threadIdx.x >> 6;
  const int lane = threadIdx.x & 63;
  const int row0 = blockIdx.x * 64 + wave * 16;
  if (row0 >= nrows) return;
  const int lm = lane & 15;   // A-row / C-col
  const int lq = lane >> 4;   // quad

  int arow = row0 + lm;
  int arowc = arow < nrows ? arow : nrows - 1;  // clamp (stores are guarded)

  short8 afrag[4];
#pragma unroll
  for (int kc = 0; kc < 4; ++kc) {
    int k0 = kc * 32 + lq * 8;
    const float4* p = (const float4*)(X + (size_t)arowc * HD + k0);
    float4 f0 = p[0], f1 = p[1];
    short8 a;
    a[0] = (short)bf16_rne(f0.x); a[1] = (short)bf16_rne(f0.y);
    a[2] = (short)bf16_rne(f0.z); a[3] = (short)bf16_rne(f0.w);
    a[4] = (short)bf16_rne(f1.x); a[5] = (short)bf16_rne(f1.y);
    a[6] = (short)bf16_rne(f1.z); a[7] = (short)bf16_rne(f1.w);
    afrag[kc] = a;
  }

  float dv[4];
#pragma unroll
  for (int r = 0; r < 4; ++r) {
    int row = row0 + lq * 4 + r;
    dv[r] = dinv[row < nrows ? row : 0];
  }

#pragma unroll
  for (int nt = 0; nt < 8; ++nt) {
    f32x4 acc = {0.f, 0.f, 0.f, 0.f};
    const unsigned short* Wb = Wt + (size_t)(nt * 16 + lm) * HD + lq * 8;
#pragma unroll
    for (int kc = 0; kc < 4; ++kc) {
      short8 bfrag = *(const short8*)(Wb + kc * 32);
      acc = __builtin_amdgcn_mfma_f32_16x16x32_bf16(afrag[kc], bfrag, acc, 0, 0, 0);
    }
#pragma unroll
    for (int r = 0; r < 4; ++r) {
      int row = row0 + lq * 4 + r;
      if (row < nrows)
        hs[((size_t)nt * NN + row) * 16 + lm] = bf16_rne(acc[r] * dv[r]);
    }
  }
}

// ---------------- plane-sharded gather, lane-pair-per-node, NO cross-lane reduce ----------------
// Block = (bucket g, plane x = blockIdx&7): 256 threads = 128 nodes x 2 feature-halves.
// Round-robin blockIdx->XCD keeps each XCD on its 3.2MB plane (L2-resident; R11/R12
// FETCH 43MB confirmed). Each lane serially walks its node's edges, accumulating its
// 8-feature half in registers — zero shfl tree (R12's 40-ds-op reduce was 300us).
// Bucket's col segment staged in LDS once, reused across all feature accesses.
__global__ __launch_bounds__(256) void k_gatherP(const uint4* __restrict__ hsP,
                                                 const float* __restrict__ dinv,
                                                 const int2* __restrict__ rows,
                                                 const int* __restrict__ col,
                                                 const int* __restrict__ gcursor,
                                                 const float* __restrict__ b1,
                                                 const float* __restrict__ uv,
                                                 float2* __restrict__ qpart) {
  __shared__ int lcol[CAP];
  const int x = blockIdx.x & 7;
  const int g = blockIdx.x >> 3;
  const int t = threadIdx.x;
  const int node0 = g * NPB;
  const int gbase = g * CAP;
  const int cnt = gcursor[g] - gbase;

  for (int i = t; i < cnt; i += 256) lcol[i] = col[gbase + i];
  __syncthreads();

  const int nl = t >> 1;        // local node 0..127
  const int fq = t & 1;         // feature half (8 feats)
  const int node = node0 + nl;
  const bool valid = node < NN;

  int2 be = valid ? rows[node] : make_int2(0, 0);
  const uint4* plane = hsP + (size_t)x * NN * 2 + fq;

  float ax[8] = {0.f, 0.f, 0.f, 0.f, 0.f, 0.f, 0.f, 0.f};
  if (valid) acc_row8(ax, plane[(size_t)node * 2]);  // self term

  int e = be.x - gbase;
  const int eend = be.y - gbase;
  for (; e + 1 < eend; e += 2) {
    int s0 = lcol[e];
    int s1 = lcol[e + 1];
    uint4 u0 = plane[(size_t)s0 * 2];
    uint4 u1 = plane[(size_t)s1 * 2];
    acc_row8(ax, u0);
    acc_row8(ax, u1);
  }
  if (e < eend) acc_row8(ax, plane[(size_t)lcol[e] * 2]);

  // epilogue: relu + partial projection over own 8 feats; combine with partner lane
  float di = valid ? dinv[node] : 0.f;
  float s1 = 0.f, s2 = 0.f;
#pragma unroll
  for (int j = 0; j < 8; ++j) {
    int f = x * 16 + fq * 8 + j;
    float h = fmaxf(di * ax[j] + b1[f], 0.f);
    s1 += h * uv[f];
    s2 += h * uv[128 + f];
  }
  s1 += __shfl_xor(s1, 1);
  s2 += __shfl_xor(s2, 1);
  if (fq == 0 && valid) qpart[(size_t)x * NN + node] = make_float2(s1, s2);
}

// ---------------- qred: q[n] = dinv[n] * sum_x qpart[x][n] ----------------
__global__ void k_qred(const float2* __restrict__ qpart, const float* __restrict__ dinv,
                       float2* __restrict__ q, int n) {
  int i = blockIdx.x * 256 + threadIdx.x;
  if (i < n) {
    float a = 0.f, b = 0.f;
#pragma unroll
    for (int xx = 0; xx < 8; ++xx) {
      float2 p = qpart[(size_t)xx * NN + i];
      a += p.x; b += p.y;
    }
    float di = dinv[i];
    q[i] = make_float2(di * a, di * b);
  }
}

// ---------------- qagg: conv2+score collapsed (q table 800KB, L2-resident) ----------------
__global__ __launch_bounds__(256) void k_qagg(const float2* __restrict__ q,
                                              const float* __restrict__ dinv,
                                              const int2* __restrict__ rows,
                                              const int* __restrict__ col,
                                              const float* __restrict__ uv,
                                              float2* __restrict__ sv, int n) {
  int i = blockIdx.x * 256 + threadIdx.x;
  if (i >= n) return;
  int2 be = rows[i];
  int beg = be.x, end = be.y;
  float2 a = q[i];
  float a1 = a.x, a2 = a.y;
  int e = beg;
  for (; e + 3 < end; e += 4) {
    float2 q0 = q[col[e]];
    float2 q1 = q[col[e + 1]];
    float2 q2 = q[col[e + 2]];
    float2 q3 = q[col[e + 3]];
    a1 += (q0.x + q1.x) + (q2.x + q3.x);
    a2 += (q0.y + q1.y) + (q2.y + q3.y);
  }
  for (; e < end; ++e) {
    float2 qq = q[col[e]];
    a1 += qq.x; a2 += qq.y;
  }
  float di = dinv[i];
  sv[i] = make_float2(a1 * di + uv[256], a2 * di + uv[257]);
}

// ---------------- pair outputs ----------------
__global__ void k_pairs(const float2* __restrict__ s, const int* __restrict__ I,
                        const int* __restrict__ J, const float* __restrict__ blin,
                        float* __restrict__ out, int np) {
  int p = blockIdx.x * 256 + threadIdx.x;
  if (p < np) {
    float v = s[I[p]].x + s[J[p]].y + blin[0];
    out[p] = 1.f / (1.f + __expf(-v));
  }
}

extern "C" void kernel_launch(void* const* d_in, const int* in_sizes, int n_in,
                              void* d_out, int out_size, void* d_ws, size_t ws_size,
                              hipStream_t stream) {
  const float* x     = (const float*)d_in[0];
  const int*   eidx  = (const int*)d_in[1];
  const int*   Iidx  = (const int*)d_in[2];
  const int*   Jidx  = (const int*)d_in[3];
  const float* W1    = (const float*)d_in[4];
  const float* b1    = (const float*)d_in[5];
  const float* W2    = (const float*)d_in[6];
  const float* b2    = (const float*)d_in[7];
  const float* Wlin  = (const float*)d_in[8];
  const float* blin  = (const float*)d_in[9];
  const int* src = eidx;
  const int* dst = eidx + NE;

  // workspace layout
  float* ws    = (float*)d_ws;
  float* dinv  = ws;                                  // 100000
  float* sv    = dinv + 100000;                       // 200000 (float2/node)
  float* qbuf  = sv + 200000;                         // 200000 (float2/node)
  float* uv    = qbuf + 200000;                       // 264
  float* qpart = uv + 264;                            // 8*NN float2 = 1600000
  unsigned short* hs = (unsigned short*)(qpart + 1600000);  // 8 planes * NN * 16 bf16
  unsigned short* wt1 = hs + (size_t)NN * HD;         // 16384 bf16
  int2* rows   = (int2*)(wt1 + 16384);                // NN int2 (8B-aligned)
  int* col     = (int*)(rows + NN);                   // NB*CAP = 2001920
  int* gcursor = col + NB * CAP;                      // NB (pad 784)
  uint2* binned = (uint2*)(gcursor + 784);            // NB*CAP x 8B

  float* out = (float*)d_out;

  // ---- CSR build (fixed-capacity buckets) ----
  k_initgcur<<<(NB + 255) / 256, 256, 0, stream>>>(gcursor);
  k_binA<<<NWG, 256, 0, stream>>>(src, dst, gcursor, binned, NE);
  k_binB<<<NB, 256, 0, stream>>>(binned, gcursor, rows, col, dinv);

  // ---- weight prep ----
  k_wconv<<<64, 256, 0, stream>>>(W1, wt1);
  k_uvec<<<1, 256, 0, stream>>>(W2, Wlin, b2, uv);

  // conv1 GEMM -> plane-layout hs
  k_gemm_mfma<<<(NN + 63) / 64, 256, 0, stream>>>(x, wt1, dinv, hs, NN);

  // conv1 aggregation + relu + score projection (plane-sharded, serial per-lane acc)
  k_gatherP<<<NB * 8, 256, 0, stream>>>((const uint4*)hs, dinv, rows, col, gcursor,
                                        b1, uv, (float2*)qpart);
  k_qred<<<(NN + 255) / 256, 256, 0, stream>>>((const float2*)qpart, dinv, (float2*)qbuf, NN);

  // conv2 + score head collapsed
  k_qagg<<<(NN + 255) / 256, 256, 0, stream>>>((const float2*)qbuf, dinv, rows, col, uv,
                                               (float2*)sv, NN);

  // pair outputs
  k_pairs<<<(NP + 255) / 256, 256, 0, stream>>>((const float2*)sv, Iidx, Jidx, blin, out, NP);
}

// Round 14
// 281.265 us; speedup vs baseline: 4.4903x; 1.0048x over previous
//
#include <hip/hip_runtime.h>
#include <hip/hip_bf16.h>
#include <math.h>

#define NN 100000
#define NE 1600000
#define NP 500000
#define HD 128
#define NPB 128                    // nodes per bucket (pow2)
#define NB 782                     // ceil(NN/NPB)
#define CAP 2560                   // bucket capacity (mean 2048, +11 sigma; validated R10-13)
#define CHUNK 4096                 // edges per binning workgroup
#define NWG 391                    // ceil(NE/CHUNK)

typedef __attribute__((ext_vector_type(8))) short short8;   // 8 bf16 = 4 VGPRs
typedef __attribute__((ext_vector_type(4))) float f32x4;

// ---- bf16 helpers ----
__device__ __forceinline__ float bf_lo(unsigned int u) { return __uint_as_float(u << 16); }
__device__ __forceinline__ float bf_hi(unsigned int u) { return __uint_as_float(u & 0xffff0000u); }
__device__ __forceinline__ unsigned short bf16_rne(float f) {
  unsigned int u = __float_as_uint(f);
  u = (u + 0x7fffu + ((u >> 16) & 1u)) >> 16;
  return (unsigned short)u;
}
// accumulate 8 bf16 (one uint4) into ax[8]
__device__ __forceinline__ void acc_row8(float* ax, uint4 u) {
  ax[0] += bf_lo(u.x); ax[1] += bf_hi(u.x);
  ax[2] += bf_lo(u.y); ax[3] += bf_hi(u.y);
  ax[4] += bf_lo(u.z); ax[5] += bf_hi(u.z);
  ax[6] += bf_lo(u.w); ax[7] += bf_hi(u.w);
}

// ---------------- cursor init: gcursor[b] = b*CAP ----------------
__global__ void k_initgcur(int* __restrict__ gcursor) {
  int b = blockIdx.x * 256 + threadIdx.x;
  if (b < NB) gcursor[b] = b * CAP;
}

// ---- binA: bin edges into fixed-capacity bucket regions; 4B entry = src | (d&127)<<17 ----
__global__ __launch_bounds__(256) void k_binA(const int* __restrict__ src,
                                              const int* __restrict__ dst,
                                              int* __restrict__ gcursor,
                                              unsigned* __restrict__ binned, int ne) {
  __shared__ int hist[NB];
  __shared__ int base[NB];
  const int t = threadIdx.x;
  const int e0 = blockIdx.x * CHUNK;

  for (int i = t; i < NB; i += 256) hist[i] = 0;
  __syncthreads();

#pragma unroll
  for (int k = 0; k < CHUNK / 256; ++k) {
    int e = e0 + k * 256 + t;
    if (e < ne) atomicAdd(&hist[dst[e] >> 7], 1);
  }
  __syncthreads();

  for (int i = t; i < NB; i += 256) {
    int c = hist[i];
    base[i] = c ? atomicAdd(&gcursor[i], c) : 0;
    hist[i] = 0;
  }
  __syncthreads();

#pragma unroll
  for (int k = 0; k < CHUNK / 256; ++k) {
    int e = e0 + k * 256 + t;
    if (e < ne) {
      int d = dst[e];
      int b = d >> 7;
      int pos = base[b] + atomicAdd(&hist[b], 1);
      binned[pos] = (unsigned)src[e] | ((unsigned)(d & 127) << 17);
    }
  }
}

// ---- binB: per-node count -> rows + dinv + degree-sorted order, then CSR placement ----
__global__ __launch_bounds__(256) void k_binB(const unsigned* __restrict__ binned,
                                              const int* __restrict__ gcursor,
                                              int2* __restrict__ rows,
                                              int* __restrict__ col,
                                              float* __restrict__ dinv,
                                              int* __restrict__ sortOrd) {
  __shared__ int hcnt[NPB];
  __shared__ int sc[NPB];
  __shared__ int lcur[NPB];
  __shared__ int h64[64];
  __shared__ int s64[64];
  const int b = blockIdx.x;
  const int t = threadIdx.x;
  const int node0 = b * NPB;
  const int node1 = (node0 + NPB > NN) ? NN : node0 + NPB;
  const int nnode = node1 - node0;
  if (t < NPB) hcnt[t] = 0;
  if (t < 64) h64[t] = 0;
  __syncthreads();

  const int gbase = b * CAP;
  const int gend = gcursor[b];   // after binA: b*CAP + bucket count
  for (int i = gbase + t; i < gend; i += 256)
    atomicAdd(&hcnt[binned[i] >> 17], 1);
  __syncthreads();

  int v = (t < NPB) ? hcnt[t] : 0;
  if (t < NPB) sc[t] = v;
  __syncthreads();
#pragma unroll
  for (int o = 1; o < NPB; o <<= 1) {
    int add = (t < NPB && t >= o) ? sc[t - o] : 0;
    __syncthreads();
    if (t < NPB) sc[t] += add;
    __syncthreads();
  }
  if (t < nnode) {
    int rp = gbase + sc[t] - v;   // exclusive prefix within bucket
    rows[node0 + t] = make_int2(rp, rp + v);
    lcur[t] = rp;
    dinv[node0 + t] = rsqrtf((float)v + 1.0f);
  }

  // ---- counting sort of the 128 local nodes by degree (invalid t -> deg 0) ----
  const int deg = (t < nnode) ? v : 0;
  const int dcl = deg > 63 ? 63 : deg;
  if (t < NPB) atomicAdd(&h64[dcl], 1);
  __syncthreads();
  int hv = (t < 64) ? h64[t] : 0;
  if (t < 64) s64[t] = hv;
  __syncthreads();
#pragma unroll
  for (int o = 1; o < 64; o <<= 1) {
    int add = (t < 64 && t >= o) ? s64[t - o] : 0;
    __syncthreads();
    if (t < 64) s64[t] += add;
    __syncthreads();
  }
  if (t < 64) h64[t] = s64[t] - hv;  // exclusive base -> cursor
  __syncthreads();
  if (t < NPB) {
    int p = atomicAdd(&h64[dcl], 1);
    sortOrd[b * NPB + p] = t;
  }
  __syncthreads();

  for (int i = gbase + t; i < gend; i += 256) {
    unsigned en = binned[i];
    int pos = atomicAdd(&lcur[en >> 17], 1);
    col[pos] = (int)(en & 0x1FFFF);
  }
}

// ---------------- W transpose+cast: Wt[n][k] = bf16(W[k][n]) ----------------
__global__ void k_wconv(const float* __restrict__ W, unsigned short* __restrict__ Wt) {
  int t = blockIdx.x * 256 + threadIdx.x;  // 16384
  int n = t >> 7, k = t & 127;
  Wt[t] = bf16_rne(W[k * HD + n]);
}

// ---------------- u-vector prep: u1 = W2@Wl[:128], u2 = W2@Wl[128:], c1/c2 = b2.Wl ----------------
// uv layout: [0..127]=u1, [128..255]=u2, [256]=c1, [257]=c2
__global__ __launch_bounds__(256) void k_uvec(const float* __restrict__ W2,
                                              const float* __restrict__ Wl,
                                              const float* __restrict__ b2,
                                              float* __restrict__ uv) {
  __shared__ float sh[256];
  const int t = threadIdx.x;
  const int half = t >> 7;
  const int k = t & 127;
  const float* wl = Wl + half * 128;
  float s = 0.f;
  for (int c = 0; c < 128; ++c) s += W2[k * HD + c] * wl[c];
  uv[half * 128 + k] = s;

  sh[t] = b2[k] * Wl[half * 128 + k];
  __syncthreads();
  for (int o = 64; o > 0; o >>= 1) {
    if ((t & 127) < o) sh[t] += sh[t + o];
    __syncthreads();
  }
  if (t == 0) uv[256] = sh[0];
  if (t == 128) uv[257] = sh[128];
}

// ---------------- MFMA GEMM -> plane layout ----------------
// plane p holds cols [16p,16p+16): ushort addr = ((p*NN + row)*16 + col_in_plane)
__global__ __launch_bounds__(256) void k_gemm_mfma(const float* __restrict__ X,
                                                   const unsigned short* __restrict__ Wt,
                                                   const float* __restrict__ dinv,
                                                   unsigned short* __restrict__ hs,
                                                   int nrows) {
  const int wave = threadIdx.x >> 6;
  const int lane = threadIdx.x & 63;
  const int row0 = blockIdx.x * 64 + wave * 16;
  if (row0 >= nrows) return;
  const int lm = lane & 15;   // A-row / C-col
  const int lq = lane >> 4;   // quad

  int arow = row0 + lm;
  int arowc = arow < nrows ? arow : nrows - 1;  // clamp (stores are guarded)

  short8 afrag[4];
#pragma unroll
  for (int kc = 0; kc < 4; ++kc) {
    int k0 = kc * 32 + lq * 8;
    const float4* p = (const float4*)(X + (size_t)arowc * HD + k0);
    float4 f0 = p[0], f1 = p[1];
    short8 a;
    a[0] = (short)bf16_rne(f0.x); a[1] = (short)bf16_rne(f0.y);
    a[2] = (short)bf16_rne(f0.z); a[3] = (short)bf16_rne(f0.w);
    a[4] = (short)bf16_rne(f1.x); a[5] = (short)bf16_rne(f1.y);
    a[6] = (short)bf16_rne(f1.z); a[7] = (short)bf16_rne(f1.w);
    afrag[kc] = a;
  }

  float dv[4];
#pragma unroll
  for (int r = 0; r < 4; ++r) {
    int row = row0 + lq * 4 + r;
    dv[r] = dinv[row < nrows ? row : 0];
  }

#pragma unroll
  for (int nt = 0; nt < 8; ++nt) {
    f32x4 acc = {0.f, 0.f, 0.f, 0.f};
    const unsigned short* Wb = Wt + (size_t)(nt * 16 + lm) * HD + lq * 8;
#pragma unroll
    for (int kc = 0; kc < 4; ++kc) {
      short8 bfrag = *(const short8*)(Wb + kc * 32);
      acc = __builtin_amdgcn_mfma_f32_16x16x32_bf16(afrag[kc], bfrag, acc, 0, 0, 0);
    }
#pragma unroll
    for (int r = 0; r < 4; ++r) {
      int row = row0 + lq * 4 + r;
      if (row < nrows)
        hs[((size_t)nt * NN + row) * 16 + lm] = bf16_rne(acc[r] * dv[r]);
    }
  }
}

// ---------------- plane-sharded gather, lane-pair-per-node, degree-sorted ----------------
// Block = (bucket g, plane x = blockIdx&7): 256 threads = 128 sorted positions x 2 halves.
// Degree sort => each wave's 32 nodes have ~equal degree (divergence ~25->~17 iters).
// Unroll-4: 4 independent 16B loads in flight per lane (plane is 3.2MB L2-resident,
// no thrash risk). Register accumulation, no shfl tree.
__global__ __launch_bounds__(256) void k_gatherP(const uint4* __restrict__ hsP,
                                                 const float* __restrict__ dinv,
                                                 const int2* __restrict__ rows,
                                                 const int* __restrict__ col,
                                                 const int* __restrict__ gcursor,
                                                 const int* __restrict__ sortOrd,
                                                 const float* __restrict__ b1,
                                                 const float* __restrict__ uv,
                                                 float2* __restrict__ qpart) {
  __shared__ int lcol[CAP];
  const int x = blockIdx.x & 7;
  const int g = blockIdx.x >> 3;
  const int t = threadIdx.x;
  const int node0 = g * NPB;
  const int gbase = g * CAP;
  const int cnt = gcursor[g] - gbase;

  for (int i = t; i < cnt; i += 256) lcol[i] = col[gbase + i];
  __syncthreads();

  const int p = t >> 1;         // sorted position 0..127
  const int fq = t & 1;         // feature half (8 feats)
  const int tloc = sortOrd[g * NPB + p];
  const int node = node0 + tloc;
  const bool valid = node < NN;

  int2 be = valid ? rows[node] : make_int2(0, 0);
  const uint4* plane = hsP + (size_t)x * NN * 2 + fq;

  float ax[8] = {0.f, 0.f, 0.f, 0.f, 0.f, 0.f, 0.f, 0.f};
  if (valid) acc_row8(ax, plane[(size_t)node * 2]);  // self term

  int e = be.x - gbase;
  const int eend = be.y - gbase;
  for (; e + 3 < eend; e += 4) {
    int s0 = lcol[e], s1 = lcol[e + 1], s2 = lcol[e + 2], s3 = lcol[e + 3];
    uint4 u0 = plane[(size_t)s0 * 2];
    uint4 u1 = plane[(size_t)s1 * 2];
    uint4 u2 = plane[(size_t)s2 * 2];
    uint4 u3 = plane[(size_t)s3 * 2];
    acc_row8(ax, u0); acc_row8(ax, u1); acc_row8(ax, u2); acc_row8(ax, u3);
  }
  for (; e < eend; ++e) acc_row8(ax, plane[(size_t)lcol[e] * 2]);

  // epilogue: relu + partial projection over own 8 feats; combine with partner lane
  float di = valid ? dinv[node] : 0.f;
  float s1 = 0.f, s2 = 0.f;
#pragma unroll
  for (int j = 0; j < 8; ++j) {
    int f = x * 16 + fq * 8 + j;
    float h = fmaxf(di * ax[j] + b1[f], 0.f);
    s1 += h * uv[f];
    s2 += h * uv[128 + f];
  }
  s1 += __shfl_xor(s1, 1);
  s2 += __shfl_xor(s2, 1);
  if (fq == 0 && valid) qpart[(size_t)x * NN + node] = make_float2(s1, s2);
}

// ---------------- qred: q[n] = dinv[n] * sum_x qpart[x][n] ----------------
__global__ void k_qred(const float2* __restrict__ qpart, const float* __restrict__ dinv,
                       float2* __restrict__ q, int n) {
  int i = blockIdx.x * 256 + threadIdx.x;
  if (i < n) {
    float a = 0.f, b = 0.f;
#pragma unroll
    for (int xx = 0; xx < 8; ++xx) {
      float2 p = qpart[(size_t)xx * NN + i];
      a += p.x; b += p.y;
    }
    float di = dinv[i];
    q[i] = make_float2(di * a, di * b);
  }
}

// ---------------- qagg: conv2+score collapsed (q table 800KB, L2-resident) ----------------
__global__ __launch_bounds__(256) void k_qagg(const float2* __restrict__ q,
                                              const float* __restrict__ dinv,
                                              const int2* __restrict__ rows,
                                              const int* __restrict__ col,
                                              const float* __restrict__ uv,
                                              float2* __restrict__ sv, int n) {
  int i = blockIdx.x * 256 + threadIdx.x;
  if (i >= n) return;
  int2 be = rows[i];
  int node0 = (i >> 7) << 7;   // bucket-local col entries hold local src ids? no: col holds global src (17b) — see binB
  int beg = be.x, end = be.y;
  float2 a = q[i];
  float a1 = a.x, a2 = a.y;
  int e = beg;
  for (; e + 3 < end; e += 4) {
    float2 q0 = q[col[e]];
    float2 q1 = q[col[e + 1]];
    float2 q2 = q[col[e + 2]];
    float2 q3 = q[col[e + 3]];
    a1 += (q0.x + q1.x) + (q2.x + q3.x);
    a2 += (q0.y + q1.y) + (q2.y + q3.y);
  }
  for (; e < end; ++e) {
    float2 qq = q[col[e]];
    a1 += qq.x; a2 += qq.y;
  }
  float di = dinv[i];
  sv[i] = make_float2(a1 * di + uv[256], a2 * di + uv[257]);
  (void)node0;
}

// ---------------- pair outputs ----------------
__global__ void k_pairs(const float2* __restrict__ s, const int* __restrict__ I,
                        const int* __restrict__ J, const float* __restrict__ blin,
                        float* __restrict__ out, int np) {
  int p = blockIdx.x * 256 + threadIdx.x;
  if (p < np) {
    float v = s[I[p]].x + s[J[p]].y + blin[0];
    out[p] = 1.f / (1.f + __expf(-v));
  }
}

extern "C" void kernel_launch(void* const* d_in, const int* in_sizes, int n_in,
                              void* d_out, int out_size, void* d_ws, size_t ws_size,
                              hipStream_t stream) {
  const float* x     = (const float*)d_in[0];
  const int*   eidx  = (const int*)d_in[1];
  const int*   Iidx  = (const int*)d_in[2];
  const int*   Jidx  = (const int*)d_in[3];
  const float* W1    = (const float*)d_in[4];
  const float* b1    = (const float*)d_in[5];
  const float* W2    = (const float*)d_in[6];
  const float* b2    = (const float*)d_in[7];
  const float* Wlin  = (const float*)d_in[8];
  const float* blin  = (const float*)d_in[9];
  const int* src = eidx;
  const int* dst = eidx + NE;

  // workspace layout (hs offset is 16B-aligned: float offset 2100264 -> byte 8401056 = 16*525066)
  float* ws    = (float*)d_ws;
  float* dinv  = ws;                                  // 100000
  float* sv    = dinv + 100000;                       // 200000 (float2/node)
  float* qbuf  = sv + 200000;                         // 200000 (float2/node)
  float* uv    = qbuf + 200000;                       // 264
  float* qpart = uv + 264;                            // 8*NN float2 = 1600000
  unsigned short* hs = (unsigned short*)(qpart + 1600000);  // 8 planes * NN * 16 bf16
  unsigned short* wt1 = hs + (size_t)NN * HD;         // 16384 bf16
  int2* rows   = (int2*)(wt1 + 16384);                // NN int2 (8B-aligned)
  int* col     = (int*)(rows + NN);                   // NB*CAP = 2001920
  int* gcursor = col + NB * CAP;                      // NB (pad 784)
  int* sortOrd = gcursor + 784;                       // NB*NPB = 100096
  unsigned* binned = (unsigned*)(sortOrd + NB * NPB); // NB*CAP x 4B

  float* out = (float*)d_out;

  // ---- CSR build (fixed-capacity buckets; 4B packed entries) ----
  k_initgcur<<<(NB + 255) / 256, 256, 0, stream>>>(gcursor);
  k_binA<<<NWG, 256, 0, stream>>>(src, dst, gcursor, binned, NE);
  k_binB<<<NB, 256, 0, stream>>>(binned, gcursor, rows, col, dinv, sortOrd);

  // ---- weight prep ----
  k_wconv<<<64, 256, 0, stream>>>(W1, wt1);
  k_uvec<<<1, 256, 0, stream>>>(W2, Wlin, b2, uv);

  // conv1 GEMM -> plane-layout hs
  k_gemm_mfma<<<(NN + 63) / 64, 256, 0, stream>>>(x, wt1, dinv, hs, NN);

  // conv1 aggregation + relu + score projection (plane-sharded, degree-sorted)
  k_gatherP<<<NB * 8, 256, 0, stream>>>((const uint4*)hs, dinv, rows, col, gcursor,
                                        sortOrd, b1, uv, (float2*)qpart);
  k_qred<<<(NN + 255) / 256, 256, 0, stream>>>((const float2*)qpart, dinv, (float2*)qbuf, NN);

  // conv2 + score head collapsed
  k_qagg<<<(NN + 255) / 256, 256, 0, stream>>>((const float2*)qbuf, dinv, rows, col, uv,
                                               (float2*)sv, NN);

  // pair outputs
  k_pairs<<<(NP + 255) / 256, 256, 0, stream>>>((const float2*)sv, Iidx, Jidx, blin, out, NP);
}